// Round 3
// baseline (322.383 us; speedup 1.0000x reference)
//
#include <hip/hip_runtime.h>

// ---------------------------------------------------------------------------
// EfficientCrossAttention on MI355X (gfx950)
// B=4 T=4096 D=1024 ; N=2048 L=768 ; H=16 dh=64
//
// R8: 8-phase 256x256 GEMM schedule (HK/m201 template, plain HIP) for
//     gemm_qkv + gemm_final. 512 thr = 8 waves (2M x 4N), per-wave 128x64.
//     A and B both staged fragment-major into a 3-slot LDS ring (96KB);
//     2 phases per BK=32 tile: {ds_read ∥ 2x gld16 stage(t+2) -> barrier ->
//     lgkmcnt(0) -> setprio(1) 16 MFMA setprio(0) -> barrier}; counted
//     s_waitcnt vmcnt(4) ONCE per tile (never 0 mid-loop).
//     R6/R7 showed depth-tuning the old 2-barrier loop is a dead end
//     (spill / util regression); this changes the phase structure instead.
//
// Fragment-major layout for X[M][K]: chunk (rt=row>>4, kb=k>>5) of 512 elems;
// within chunk: elem (p=(k>>3)&3, ri=row&15, ko=k&7) at p*128 + ri*8 + ko.
// A wave reading a chunk at lane*16B gets the 16x16x32 MFMA operand layout;
// chunks stage to LDS with linear gld16 (wave-uniform base + lane*16B).
// ---------------------------------------------------------------------------

#define DEV __device__ __forceinline__

typedef unsigned short bf16_t;
typedef __attribute__((ext_vector_type(8))) __bf16 bf16x8;
typedef __attribute__((ext_vector_type(8))) unsigned short ushort8;
typedef __attribute__((ext_vector_type(4))) float f32x4;

DEV unsigned short f2bf(float f) {            // RNE float->bf16 (finite inputs)
  unsigned int u = __float_as_uint(f);
  unsigned int r = 0x7FFFu + ((u >> 16) & 1u);
  return (unsigned short)((u + r) >> 16);
}
DEV float bf2f(unsigned short u) { return __uint_as_float(((unsigned int)u) << 16); }

DEV void gld16(const void* g, void* l) {      // async global->LDS, 16B/lane
  __builtin_amdgcn_global_load_lds((__attribute__((address_space(1))) void*)g,
                                   (__attribute__((address_space(3))) void*)l, 16, 0, 0);
}

#define BARRIER() asm volatile("s_barrier" ::: "memory")
#define WAIT_LGKM0() asm volatile("s_waitcnt lgkmcnt(0)" ::: "memory")

// ---------------------------------------------------------------------------
// 8-phase K-loop. LDS ring: 3 slots x 16384 elems (A [0,8192), B [8192,16384)).
// Per tile t (slot rd = t%3, stage slot st = (t+2)%3 = previous rd):
//   P0: ds_read B frags(4) + A frags mi 0-3 (4); stage A(t+2) (2 gld16);
//       barrier; lgkm0; setprio1; 16 MFMA (acc[0..3][*]); setprio0; barrier
//   P1: ds_read A frags mi 4-7; stage B(t+2) (2 gld16);
//       vmcnt(4)  [retires t+1's 4 stages, leaves t+2's 4 in flight];
//       barrier; lgkm0; setprio1; 16 MFMA (acc[4..7][*]); setprio0; barrier
// Ledger: 4 stage instr/wave/tile, groups stay contiguous -> vmcnt(4) exact.
// WAR: slot st's last readers ds_read'd 2 memory-clobbered barriers earlier.
// Epilogue tiles: t=nt-2 waits vmcnt(0) (drain), t=nt-1 no wait.
// ---------------------------------------------------------------------------
DEV void kloop8(int nt, const bf16_t* __restrict__ A, const bf16_t* __restrict__ BT,
                bf16_t* lds, int bm16, int bn16, int tid, f32x4 (&acc)[8][4]) {
  const int lane = tid & 63, wid = tid >> 6;
  const int wm = wid & 1, wn = wid >> 1;
  const unsigned l8 = lane * 8;

  // stage sources: wave w stages A row-tiles {w, 8+w}, B col-tiles {w, 8+w}
  const bf16_t* aw0 = A + ((size_t)(bm16 + wid) * nt) * 512 + l8;
  const bf16_t* aw1 = aw0 + (size_t)8 * nt * 512;
  const bf16_t* bw0 = BT + ((size_t)(bn16 + wid) * nt) * 512 + l8;
  const bf16_t* bw1 = bw0 + (size_t)8 * nt * 512;
  const unsigned ldsA0 = wid * 512 + l8;
  const unsigned ldsA1 = (8 + wid) * 512 + l8;
  const unsigned ldsB0 = 8192 + wid * 512 + l8;
  const unsigned ldsB1 = 8192 + (8 + wid) * 512 + l8;
  // read bases
  const unsigned rdA = (wm * 8) * 512 + l8;
  const unsigned rdB = 8192 + (wn * 4) * 512 + l8;

  // prologue: stage tile 0 -> slot 0, tile 1 -> slot 1
  gld16(aw0, (void*)&lds[ldsA0]);
  gld16(aw1, (void*)&lds[ldsA1]);
  gld16(bw0, (void*)&lds[ldsB0]);
  gld16(bw1, (void*)&lds[ldsB1]);
  gld16(aw0 + 512, (void*)&lds[16384 + ldsA0]);
  gld16(aw1 + 512, (void*)&lds[16384 + ldsA1]);
  gld16(bw0 + 512, (void*)&lds[16384 + ldsB0]);
  gld16(bw1 + 512, (void*)&lds[16384 + ldsB1]);
  aw0 += 1024; aw1 += 1024; bw0 += 1024; bw1 += 1024;   // now point at tile 2
  asm volatile("s_waitcnt vmcnt(4)\n\ts_barrier" ::: "memory");  // tile 0 landed

  unsigned rd = 0, st = 32768;
  for (int t = 0; t < nt; ++t) {
    const bool stg = (t + 2 < nt);
    bf16x8 b[4], a[4];
    // ---- P0 ----
#pragma unroll
    for (int ni = 0; ni < 4; ++ni)
      b[ni] = *(const bf16x8*)&lds[rd + rdB + ni * 512];
#pragma unroll
    for (int mi = 0; mi < 4; ++mi)
      a[mi] = *(const bf16x8*)&lds[rd + rdA + mi * 512];
    if (stg) { gld16(aw0, (void*)&lds[st + ldsA0]); gld16(aw1, (void*)&lds[st + ldsA1]); }
    BARRIER();
    WAIT_LGKM0();
    __builtin_amdgcn_s_setprio(1);
#pragma unroll
    for (int mi = 0; mi < 4; ++mi)
#pragma unroll
      for (int ni = 0; ni < 4; ++ni)
        acc[mi][ni] = __builtin_amdgcn_mfma_f32_16x16x32_bf16(a[mi], b[ni], acc[mi][ni], 0, 0, 0);
    __builtin_amdgcn_s_setprio(0);
    BARRIER();
    // ---- P1 ----
#pragma unroll
    for (int mi = 0; mi < 4; ++mi)
      a[mi] = *(const bf16x8*)&lds[rd + rdA + 2048 + mi * 512];
    if (stg) { gld16(bw0, (void*)&lds[st + ldsB0]); gld16(bw1, (void*)&lds[st + ldsB1]); }
    if (stg)             asm volatile("s_waitcnt vmcnt(4)" ::: "memory");
    else if (t + 1 < nt) asm volatile("s_waitcnt vmcnt(0)" ::: "memory");
    BARRIER();
    WAIT_LGKM0();
    __builtin_amdgcn_s_setprio(1);
#pragma unroll
    for (int mi = 0; mi < 4; ++mi)
#pragma unroll
      for (int ni = 0; ni < 4; ++ni)
        acc[4 + mi][ni] = __builtin_amdgcn_mfma_f32_16x16x32_bf16(a[mi], b[ni], acc[4 + mi][ni], 0, 0, 0);
    __builtin_amdgcn_s_setprio(0);
    BARRIER();
    st = rd; rd = (rd == 32768u) ? 0u : rd + 16384u;
    aw0 += 512; aw1 += 512; bw0 += 512; bw1 += 512;
  }
}

// ---------------------------------------------------------------------------
// Weight prep: W (K x 1024 f32, k-major) -> Wf fragment-major bf16 over
// (n=row, k). 32x32 tiles. KB = K/32.
// ---------------------------------------------------------------------------
__global__ __launch_bounds__(256) void wprep_kernel(
    const float* __restrict__ Wq, const float* __restrict__ Wk,
    const float* __restrict__ Wv, const float* __restrict__ Wh,
    bf16_t* __restrict__ Wqf, bf16_t* __restrict__ Wkf,
    bf16_t* __restrict__ Wvf, bf16_t* __restrict__ Whf) {
  int t = blockIdx.x;
  const float* src; bf16_t* dst; int KB;
  if (t < 1024)      { src = Wq; dst = Wqf; KB = 32; }
  else if (t < 1792) { src = Wk; dst = Wkf; KB = 24; t -= 1024; }
  else if (t < 2560) { src = Wv; dst = Wvf; KB = 24; t -= 1792; }
  else               { src = Wh; dst = Whf; KB = 32; t -= 2560; }
  int tk = t >> 5, tn = t & 31;
  __shared__ float tile[32][33];
  int tx = threadIdx.x & 31, ty = threadIdx.x >> 5;
#pragma unroll
  for (int i = 0; i < 4; ++i) {
    int r = ty + i * 8;
    tile[r][tx] = src[(size_t)(tk * 32 + r) * 1024 + tn * 32 + tx];
  }
  __syncthreads();
  int tid = threadIdx.x;
  if (tid < 128) {
    int rt = tid >> 6, p = (tid >> 4) & 3, ri = tid & 15;
    ushort8 v;
#pragma unroll
    for (int ko = 0; ko < 8; ++ko)
      v[ko] = f2bf(tile[p * 8 + ko][rt * 16 + ri]);
    size_t off = ((size_t)(tn * 2 + rt) * KB + tk) * 512 + p * 128 + ri * 8;
    *(ushort8*)&dst[off] = v;
  }
}

// ---------------------------------------------------------------------------
// LayerNorm x1: block = 16 rows. Phase A: coalesced read + sums + bf16 stash
// in LDS. Phase B: lanes=rows, write fragment-major (contiguous 256B runs).
// Outputs: nx1f (normalized), x1f (raw copy), both fragment-major bf16.
// ---------------------------------------------------------------------------
__global__ __launch_bounds__(256) void ln1_kernel(
    const float* __restrict__ x1, const float* __restrict__ g1, const float* __restrict__ b1,
    bf16_t* __restrict__ nx1f, bf16_t* __restrict__ x1f) {
  __shared__ bf16_t stash[16 * 1032];            // rows padded +8 elems
  __shared__ float murs[16][2];
  int rt = blockIdx.x, tid = threadIdx.x;
  {
    int rowl = tid >> 4, ci = tid & 15;
    size_t base = ((size_t)rt * 16 + rowl) * 1024;
    float s = 0.f, s2 = 0.f;
#pragma unroll
    for (int j = 0; j < 16; ++j) {
      int k0 = ci * 4 + j * 64;
      float4 f = *(const float4*)&x1[base + k0];
      s += f.x + f.y + f.z + f.w;
      s2 += f.x * f.x + f.y * f.y + f.z * f.z + f.w * f.w;
      ushort4 u;
      u.x = f2bf(f.x); u.y = f2bf(f.y); u.z = f2bf(f.z); u.w = f2bf(f.w);
      *(ushort4*)&stash[rowl * 1032 + k0] = u;
    }
#pragma unroll
    for (int off = 1; off < 16; off <<= 1) {
      s  += __shfl_xor(s, off);
      s2 += __shfl_xor(s2, off);
    }
    if (ci == 0) {
      float mu = s * (1.0f / 1024.0f);
      float var = s2 * (1.0f / 1024.0f) - mu * mu;
      murs[rowl][0] = mu;
      murs[rowl][1] = rsqrtf(var + 1e-5f);
    }
  }
  __syncthreads();
  {
    int ri = tid & 15, pg = tid >> 4;
    float mu = murs[ri][0], rs = murs[ri][1];
#pragma unroll
    for (int t = 0; t < 8; ++t) {
      int P = pg * 8 + t;                          // piece 0..127
      ushort8 raw = *(const ushort8*)&stash[ri * 1032 + P * 8];
      float4 ga = *(const float4*)&g1[P * 8], gb = *(const float4*)&g1[P * 8 + 4];
      float4 ba = *(const float4*)&b1[P * 8], bb = *(const float4*)&b1[P * 8 + 4];
      float gv[8] = {ga.x, ga.y, ga.z, ga.w, gb.x, gb.y, gb.z, gb.w};
      float bv[8] = {ba.x, ba.y, ba.z, ba.w, bb.x, bb.y, bb.z, bb.w};
      ushort8 nv;
#pragma unroll
      for (int ko = 0; ko < 8; ++ko)
        nv[ko] = f2bf((bf2f(raw[ko]) - mu) * rs * gv[ko] + bv[ko]);
      size_t off = ((size_t)rt * 32 + (P >> 2)) * 512 + (P & 3) * 128 + ri * 8;
      *(ushort8*)&nx1f[off] = nv;
      *(ushort8*)&x1f[off] = raw;
    }
  }
}

// ---------------------------------------------------------------------------
// LayerNorm x2 (rows of 768) -> nx2f fragment-major bf16. Same structure.
// ---------------------------------------------------------------------------
__global__ __launch_bounds__(256) void ln2_kernel(
    const float* __restrict__ x2, const float* __restrict__ g2, const float* __restrict__ b2,
    bf16_t* __restrict__ nx2f) {
  __shared__ bf16_t stash[16 * 776];
  __shared__ float murs[16][2];
  int rt = blockIdx.x, tid = threadIdx.x;
  {
    int rowl = tid >> 4, ci = tid & 15;
    size_t base = ((size_t)rt * 16 + rowl) * 768;
    float s = 0.f, s2 = 0.f;
#pragma unroll
    for (int j = 0; j < 12; ++j) {
      int k0 = ci * 4 + j * 64;
      float4 f = *(const float4*)&x2[base + k0];
      s += f.x + f.y + f.z + f.w;
      s2 += f.x * f.x + f.y * f.y + f.z * f.z + f.w * f.w;
      ushort4 u;
      u.x = f2bf(f.x); u.y = f2bf(f.y); u.z = f2bf(f.z); u.w = f2bf(f.w);
      *(ushort4*)&stash[rowl * 776 + k0] = u;
    }
#pragma unroll
    for (int off = 1; off < 16; off <<= 1) {
      s  += __shfl_xor(s, off);
      s2 += __shfl_xor(s2, off);
    }
    if (ci == 0) {
      float mu = s * (1.0f / 768.0f);
      float var = s2 * (1.0f / 768.0f) - mu * mu;
      murs[rowl][0] = mu;
      murs[rowl][1] = rsqrtf(var + 1e-5f);
    }
  }
  __syncthreads();
  {
    int ri = tid & 15, pg = tid >> 4;
    float mu = murs[ri][0], rs = murs[ri][1];
#pragma unroll
    for (int t = 0; t < 6; ++t) {
      int P = pg * 6 + t;                          // piece 0..95
      ushort8 raw = *(const ushort8*)&stash[ri * 776 + P * 8];
      float4 ga = *(const float4*)&g2[P * 8], gb = *(const float4*)&g2[P * 8 + 4];
      float4 ba = *(const float4*)&b2[P * 8], bb = *(const float4*)&b2[P * 8 + 4];
      float gv[8] = {ga.x, ga.y, ga.z, ga.w, gb.x, gb.y, gb.z, gb.w};
      float bv[8] = {ba.x, ba.y, ba.z, ba.w, bb.x, bb.y, bb.z, bb.w};
      ushort8 nv;
#pragma unroll
      for (int ko = 0; ko < 8; ++ko)
        nv[ko] = f2bf((bf2f(raw[ko]) - mu) * rs * gv[ko] + bv[ko]);
      size_t off = ((size_t)rt * 24 + (P >> 2)) * 512 + (P & 3) * 128 + ri * 8;
      *(ushort8*)&nx2f[off] = nv;
    }
  }
}

// ---------------------------------------------------------------------------
// Merged q/k/v GEMM, 8-phase 256x256. 512 thr = 8 waves (2M x 4N); each wave
// owns 128 rows x 64 cols = exactly ONE head (softmax within 16-lane groups).
//   [0,256):   q = softmax(nx1 @ Wq + bq), nt=32, bm=id>>2 (64), bn=id&3
//   [256,384): k = softmax(nx2 @ Wk + bk), nt=24, bm (32), bn=id&3
//   [384,512): v =          nx2 @ Wv + bv
// ---------------------------------------------------------------------------
__global__ __launch_bounds__(512, 2) void gemm_qkv_kernel(
    const bf16_t* __restrict__ nx1f, const bf16_t* __restrict__ Wqf,
    const float* __restrict__ bq, bf16_t* __restrict__ qout,
    const bf16_t* __restrict__ nx2f, const bf16_t* __restrict__ Wkf,
    const float* __restrict__ bk, bf16_t* __restrict__ kout,
    const bf16_t* __restrict__ Wvf, const float* __restrict__ bv,
    bf16_t* __restrict__ vout) {
  __shared__ bf16_t lds[49152];                  // 3 slots x 32KB
  int id = blockIdx.x;
  const bf16_t *A, *BT; const float* bias; bf16_t* out;
  int nt, bm, bn, do_softmax;
  if (id < 256) {
    A = nx1f; BT = Wqf; bias = bq; out = qout; nt = 32;
    bm = id >> 2; bn = id & 3; do_softmax = 1;
  } else if (id < 384) {
    id -= 256; A = nx2f; BT = Wkf; bias = bk; out = kout; nt = 24;
    bm = id >> 2; bn = id & 3; do_softmax = 1;
  } else {
    id -= 384; A = nx2f; BT = Wvf; bias = bv; out = vout; nt = 24;
    bm = id >> 2; bn = id & 3; do_softmax = 0;
  }
  int tid = threadIdx.x, lane = tid & 63, wid = tid >> 6;
  int wm = wid & 1, wn = wid >> 1;

  f32x4 acc[8][4];
#pragma unroll
  for (int i = 0; i < 8; ++i)
#pragma unroll
    for (int j = 0; j < 4; ++j) acc[i][j] = {0.f, 0.f, 0.f, 0.f};

  kloop8(nt, A, BT, lds, bm * 16, bn * 16, tid, acc);

  // epilogue: one head per wave, softmax over its 64 cols
  int cg0 = bn * 256 + wn * 64;
  float bvv[4];
#pragma unroll
  for (int ni = 0; ni < 4; ++ni) bvv[ni] = bias[cg0 + ni * 16 + (lane & 15)];
  int rowbase = bm * 256 + wm * 128;
#pragma unroll
  for (int mi = 0; mi < 8; ++mi) {
#pragma unroll
    for (int r = 0; r < 4; ++r) {
      int row = rowbase + mi * 16 + (lane >> 4) * 4 + r;
      float vx[4];
#pragma unroll
      for (int ni = 0; ni < 4; ++ni) vx[ni] = acc[mi][ni][r] + bvv[ni];
      if (do_softmax) {
        // logits ~N(0,1): exp w/o max-pass is safe
        float ssum = 0.f;
#pragma unroll
        for (int ni = 0; ni < 4; ++ni) { vx[ni] = __expf(vx[ni]); ssum += vx[ni]; }
#pragma unroll
        for (int off = 1; off < 16; off <<= 1) ssum += __shfl_xor(ssum, off);
        float inv = 1.0f / ssum;
#pragma unroll
        for (int ni = 0; ni < 4; ++ni) vx[ni] *= inv;
      }
#pragma unroll
      for (int ni = 0; ni < 4; ++ni)
        out[(size_t)row * 1024 + cg0 + ni * 16 + (lane & 15)] = f2bf(vx[ni]);
    }
  }
}

// ---------------------------------------------------------------------------
// attn partials: block = (bh, n-chunk of 256); acc 64x64 outer products.
// ---------------------------------------------------------------------------
__global__ __launch_bounds__(256) void attn_partial_kernel(
    const bf16_t* __restrict__ kq, const bf16_t* __restrict__ vq,
    float* __restrict__ part) {
  int bh = blockIdx.x >> 3, c = blockIdx.x & 7;
  int b = bh >> 4, h = bh & 15;
  int tid = threadIdx.x;
  int td = tid & 15, tl = tid >> 4;
  __shared__ float ks[32][64];
  __shared__ float vs[32][64];
  float acc[4][4];
#pragma unroll
  for (int i = 0; i < 4; ++i)
#pragma unroll
    for (int j = 0; j < 4; ++j) acc[i][j] = 0.f;
  for (int s = 0; s < 8; ++s) {
    __syncthreads();
    int nr = tid >> 3, col = (tid & 7) * 8;
    int n = c * 256 + s * 32 + nr;
    size_t goff = ((size_t)(b * 2048 + n)) * 1024 + h * 64 + col;
    ushort8 lk = *(const ushort8*)&kq[goff];
    ushort8 lv = *(const ushort8*)&vq[goff];
#pragma unroll
    for (int j = 0; j < 8; ++j) {
      ks[nr][col + j] = bf2f(lk[j]);
      vs[nr][col + j] = bf2f(lv[j]);
    }
    __syncthreads();
#pragma unroll
    for (int nn = 0; nn < 32; ++nn) {
      float4 kv = *(const float4*)&ks[nn][td * 4];
      float4 vv = *(const float4*)&vs[nn][tl * 4];
      float ka[4] = {kv.x, kv.y, kv.z, kv.w};
      float va[4] = {vv.x, vv.y, vv.z, vv.w};
#pragma unroll
      for (int i = 0; i < 4; ++i)
#pragma unroll
        for (int j = 0; j < 4; ++j) acc[i][j] += ka[i] * va[j];
    }
  }
#pragma unroll
  for (int i = 0; i < 4; ++i)
#pragma unroll
    for (int j = 0; j < 4; ++j) {
      int d = td * 4 + i, l = tl * 4 + j;
      part[(((size_t)bh * 8 + c) * 64 + d) * 64 + l] = acc[i][j];
    }
}

// attnT[bh][l][d] = bf16( sum_c partial[bh][c][d][l] )
__global__ __launch_bounds__(256) void attn_finalize_kernel(
    const float* __restrict__ part, bf16_t* __restrict__ attnT) {
  int bh = blockIdx.x, tid = threadIdx.x;
  for (int t = tid; t < 4096; t += 256) {
    int d = t >> 6, l = t & 63;
    float s = 0.f;
#pragma unroll
    for (int c = 0; c < 8; ++c)
      s += part[(((size_t)bh * 8 + c) * 64 + d) * 64 + l];
    attnT[((size_t)bh * 64 + l) * 64 + d] = f2bf(s);
  }
}

// ---------------------------------------------------------------------------
// Final GEMM: out = x1 @ Wh + bh + q @ blockdiag(attn), fp32 out.
// 8-phase kloop (A = x1f, B = Whf). grid (64, 4), 512 thr. One head per wave.
// y-tail: 2 direct K-steps on (qb, attnT).
// ---------------------------------------------------------------------------
__global__ __launch_bounds__(512, 2) void gemm_final_kernel(
    const bf16_t* __restrict__ x1f, const bf16_t* __restrict__ Whf,
    const float* __restrict__ bias, const bf16_t* __restrict__ qb,
    const bf16_t* __restrict__ attnT, float* __restrict__ out) {
  __shared__ bf16_t lds[49152];
  int tid = threadIdx.x;
  int bm = blockIdx.x, bn = blockIdx.y;
  int lane = tid & 63, wid = tid >> 6;
  int wm = wid & 1, wn = wid >> 1;
  int b = bm >> 4;                       // 16 m-blocks per batch
  int klane = (lane >> 4) * 8;

  f32x4 acc[8][4];
#pragma unroll
  for (int i = 0; i < 8; ++i)
#pragma unroll
    for (int j = 0; j < 4; ++j) acc[i][j] = {0.f, 0.f, 0.f, 0.f};

  kloop8(32, x1f, Whf, lds, bm * 16, bn * 16, tid, acc);

  // --- y tail: 2 K-steps on (q, attnT). Wave col range = head h. ---
  {
    int h = bn * 4 + wn;
    size_t bh64 = ((size_t)(b * 16 + h)) * 64;
    int rowb = bm * 256 + wm * 128;
#pragma unroll
    for (int k2 = 0; k2 < 2; ++k2) {
      bf16x8 aq[8], bt[4];
#pragma unroll
      for (int mi = 0; mi < 8; ++mi)
        aq[mi] = *(const bf16x8*)(qb
            + (size_t)(rowb + mi * 16 + (lane & 15)) * 1024
            + h * 64 + k2 * 32 + klane);
#pragma unroll
      for (int ni = 0; ni < 4; ++ni)
        bt[ni] = *(const bf16x8*)(attnT
            + (bh64 + ni * 16 + (lane & 15)) * 64 + k2 * 32 + klane);
#pragma unroll
      for (int mi = 0; mi < 8; ++mi)
#pragma unroll
        for (int ni = 0; ni < 4; ++ni)
          acc[mi][ni] = __builtin_amdgcn_mfma_f32_16x16x32_bf16(aq[mi], bt[ni], acc[mi][ni], 0, 0, 0);
    }
  }

  int cg0 = bn * 256 + wn * 64;
  float bvv[4];
#pragma unroll
  for (int ni = 0; ni < 4; ++ni) bvv[ni] = bias[cg0 + ni * 16 + (lane & 15)];
  int rowbase = bm * 256 + wm * 128;
#pragma unroll
  for (int mi = 0; mi < 8; ++mi)
#pragma unroll
    for (int r = 0; r < 4; ++r) {
      int row = rowbase + mi * 16 + (lane >> 4) * 4 + r;
#pragma unroll
      for (int ni = 0; ni < 4; ++ni)
        out[(size_t)row * 1024 + cg0 + ni * 16 + (lane & 15)] = acc[mi][ni][r] + bvv[ni];
    }
}

// ---------------------------------------------------------------------------
extern "C" void kernel_launch(void* const* d_in, const int* in_sizes, int n_in,
                              void* d_out, int out_size, void* d_ws, size_t ws_size,
                              hipStream_t stream) {
  const float* x1 = (const float*)d_in[0];
  const float* x2 = (const float*)d_in[1];
  const float* Wq = (const float*)d_in[2];
  const float* bq = (const float*)d_in[3];
  const float* Wk = (const float*)d_in[4];
  const float* bk = (const float*)d_in[5];
  const float* Wv = (const float*)d_in[6];
  const float* bv = (const float*)d_in[7];
  const float* Wh = (const float*)d_in[8];
  const float* bh = (const float*)d_in[9];
  const float* g1 = (const float*)d_in[10];
  const float* b1 = (const float*)d_in[11];
  const float* g2 = (const float*)d_in[12];
  const float* b2 = (const float*)d_in[13];
  float* out = (float*)d_out;

  char* w = (char*)d_ws;
  bf16_t* nx1f = (bf16_t*)w; w += (size_t)16384 * 1024 * 2;
  bf16_t* x1f  = (bf16_t*)w; w += (size_t)16384 * 1024 * 2;
  bf16_t* nx2f = (bf16_t*)w; w += (size_t)8192 * 768 * 2;
  bf16_t* Wqf  = (bf16_t*)w; w += (size_t)1024 * 1024 * 2;
  bf16_t* Wkf  = (bf16_t*)w; w += (size_t)1024 * 768 * 2;
  bf16_t* Wvf  = (bf16_t*)w; w += (size_t)1024 * 768 * 2;
  bf16_t* Whf  = (bf16_t*)w; w += (size_t)1024 * 1024 * 2;
  bf16_t* qb   = (bf16_t*)w; w += (size_t)16384 * 1024 * 2;
  bf16_t* kbuf = (bf16_t*)w; w += (size_t)8192 * 1024 * 2;
  bf16_t* vbuf = (bf16_t*)w; w += (size_t)8192 * 1024 * 2;
  float*  part = (float*)w;  w += (size_t)64 * 8 * 64 * 64 * 4;
  bf16_t* attnT = (bf16_t*)w; w += (size_t)64 * 64 * 64 * 2;

  wprep_kernel<<<dim3(3584), dim3(256), 0, stream>>>(Wq, Wk, Wv, Wh, Wqf, Wkf, Wvf, Whf);
  ln1_kernel<<<dim3(1024), dim3(256), 0, stream>>>(x1, g1, b1, nx1f, x1f);
  ln2_kernel<<<dim3(512), dim3(256), 0, stream>>>(x2, g2, b2, nx2f);
  gemm_qkv_kernel<<<dim3(512), dim3(512), 0, stream>>>(
      nx1f, Wqf, bq, qb, nx2f, Wkf, bk, kbuf, Wvf, bv, vbuf);
  attn_partial_kernel<<<dim3(512), dim3(256), 0, stream>>>(kbuf, vbuf, part);
  attn_finalize_kernel<<<dim3(64), dim3(256), 0, stream>>>(part, attnT);
  gemm_final_kernel<<<dim3(64, 4), dim3(512), 0, stream>>>(x1f, Whf, bh, qb, attnT, out);
}

// Round 4
// 299.314 us; speedup vs baseline: 1.0771x; 1.0771x over previous
//
#include <hip/hip_runtime.h>

// ---------------------------------------------------------------------------
// EfficientCrossAttention on MI355X (gfx950)
// B=4 T=4096 D=1024 ; N=2048 L=768 ; H=16 dh=64
//
// R9: GEMMs reverted to the verified R5 structure (fragment-major operands,
//     A direct from global, B staged dbuf LDS, vmcnt(8) pipeline) after
//     R6/R7/R8 structural experiments all regressed (spill / L2 thrash /
//     1-block-CU barrier exposure). New in R9:
//       - prep_kernel: wprep + ln1 + ln2 merged into one launch (5120 blocks)
//       - attn_partial: MFMA (16x16x32 bf16) with transposed LDS staging
//         instead of scalar VALU outer products.
//
// Fragment-major layout for X[M][K]: chunk (rt=row>>4, kb=k>>5) of 512 elems;
// within chunk: elem (p=(k>>3)&3, ri=row&15, ko=k&7) at p*128 + ri*8 + ko.
// A wave reading rows rt*16..+15, k-piece p=lane>>4 reads chunk + lane*16B.
// ---------------------------------------------------------------------------

#define DEV __device__ __forceinline__

typedef unsigned short bf16_t;
typedef __attribute__((ext_vector_type(8))) __bf16 bf16x8;
typedef __attribute__((ext_vector_type(8))) unsigned short ushort8;
typedef __attribute__((ext_vector_type(4))) float f32x4;

DEV unsigned short f2bf(float f) {            // RNE float->bf16 (finite inputs)
  unsigned int u = __float_as_uint(f);
  unsigned int r = 0x7FFFu + ((u >> 16) & 1u);
  return (unsigned short)((u + r) >> 16);
}
DEV float bf2f(unsigned short u) { return __uint_as_float(((unsigned int)u) << 16); }

DEV void gld16(const void* g, void* l) {      // async global->LDS, 16B/lane
  __builtin_amdgcn_global_load_lds((__attribute__((address_space(1))) void*)g,
                                   (__attribute__((address_space(3))) void*)l, 16, 0, 0);
}

// ---------------------------------------------------------------------------
// prep_kernel: merged wprep (blocks [0,3584)), ln1 ([3584,4608)),
// ln2 ([4608,5120)). All independent, memory-bound; one launch kills two
// inter-kernel gaps. Shared LDS buffer = max of the three needs (33KB).
// ---------------------------------------------------------------------------
__global__ __launch_bounds__(256) void prep_kernel(
    const float* __restrict__ Wq, const float* __restrict__ Wk,
    const float* __restrict__ Wv, const float* __restrict__ Wh,
    bf16_t* __restrict__ Wqf, bf16_t* __restrict__ Wkf,
    bf16_t* __restrict__ Wvf, bf16_t* __restrict__ Whf,
    const float* __restrict__ x1, const float* __restrict__ g1,
    const float* __restrict__ b1, bf16_t* __restrict__ nx1f,
    bf16_t* __restrict__ x1f,
    const float* __restrict__ x2, const float* __restrict__ g2,
    const float* __restrict__ b2, bf16_t* __restrict__ nx2f) {
  __shared__ __align__(16) char smem[16 * 1032 * 2];   // 33024 B
  __shared__ float murs[16][2];
  int blk = blockIdx.x, tid = threadIdx.x;

  if (blk < 3584) {
    // ---------------- wprep: W (K x 1024 f32) -> fragment-major bf16 -------
    int t = blk;
    const float* src; bf16_t* dst; int KB;
    if (t < 1024)      { src = Wq; dst = Wqf; KB = 32; }
    else if (t < 1792) { src = Wk; dst = Wkf; KB = 24; t -= 1024; }
    else if (t < 2560) { src = Wv; dst = Wvf; KB = 24; t -= 1792; }
    else               { src = Wh; dst = Whf; KB = 32; t -= 2560; }
    int tk = t >> 5, tn = t & 31;
    float (*tile)[33] = (float(*)[33])smem;
    int tx = tid & 31, ty = tid >> 5;
#pragma unroll
    for (int i = 0; i < 4; ++i) {
      int r = ty + i * 8;
      tile[r][tx] = src[(size_t)(tk * 32 + r) * 1024 + tn * 32 + tx];
    }
    __syncthreads();
    if (tid < 128) {
      int rt = tid >> 6, p = (tid >> 4) & 3, ri = tid & 15;
      ushort8 v;
#pragma unroll
      for (int ko = 0; ko < 8; ++ko)
        v[ko] = f2bf(tile[p * 8 + ko][rt * 16 + ri]);
      size_t off = ((size_t)(tn * 2 + rt) * KB + tk) * 512 + p * 128 + ri * 8;
      *(ushort8*)&dst[off] = v;
    }
    return;
  }

  if (blk < 4608) {
    // ---------------- ln1: rows of 1024 -> nx1f + x1f fragment-major -------
    bf16_t* stash = (bf16_t*)smem;                  // rows padded to 1032
    int rt = blk - 3584;
    {
      int rowl = tid >> 4, ci = tid & 15;
      size_t base = ((size_t)rt * 16 + rowl) * 1024;
      float s = 0.f, s2 = 0.f;
#pragma unroll
      for (int j = 0; j < 16; ++j) {
        int k0 = ci * 4 + j * 64;
        float4 f = *(const float4*)&x1[base + k0];
        s += f.x + f.y + f.z + f.w;
        s2 += f.x * f.x + f.y * f.y + f.z * f.z + f.w * f.w;
        ushort4 u;
        u.x = f2bf(f.x); u.y = f2bf(f.y); u.z = f2bf(f.z); u.w = f2bf(f.w);
        *(ushort4*)&stash[rowl * 1032 + k0] = u;
      }
#pragma unroll
      for (int off = 1; off < 16; off <<= 1) {
        s  += __shfl_xor(s, off);
        s2 += __shfl_xor(s2, off);
      }
      if (ci == 0) {
        float mu = s * (1.0f / 1024.0f);
        float var = s2 * (1.0f / 1024.0f) - mu * mu;
        murs[rowl][0] = mu;
        murs[rowl][1] = rsqrtf(var + 1e-5f);
      }
    }
    __syncthreads();
    {
      int ri = tid & 15, pg = tid >> 4;
      float mu = murs[ri][0], rs = murs[ri][1];
#pragma unroll
      for (int t = 0; t < 8; ++t) {
        int P = pg * 8 + t;                          // piece 0..127
        ushort8 raw = *(const ushort8*)&stash[ri * 1032 + P * 8];
        float4 ga = *(const float4*)&g1[P * 8], gb = *(const float4*)&g1[P * 8 + 4];
        float4 ba = *(const float4*)&b1[P * 8], bb = *(const float4*)&b1[P * 8 + 4];
        float gv[8] = {ga.x, ga.y, ga.z, ga.w, gb.x, gb.y, gb.z, gb.w};
        float bv[8] = {ba.x, ba.y, ba.z, ba.w, bb.x, bb.y, bb.z, bb.w};
        ushort8 nv;
#pragma unroll
        for (int ko = 0; ko < 8; ++ko)
          nv[ko] = f2bf((bf2f(raw[ko]) - mu) * rs * gv[ko] + bv[ko]);
        size_t off = ((size_t)rt * 32 + (P >> 2)) * 512 + (P & 3) * 128 + ri * 8;
        *(ushort8*)&nx1f[off] = nv;
        *(ushort8*)&x1f[off] = raw;
      }
    }
    return;
  }

  {
    // ---------------- ln2: rows of 768 -> nx2f fragment-major --------------
    bf16_t* stash = (bf16_t*)smem;                  // rows padded to 776
    int rt = blk - 4608;
    {
      int rowl = tid >> 4, ci = tid & 15;
      size_t base = ((size_t)rt * 16 + rowl) * 768;
      float s = 0.f, s2 = 0.f;
#pragma unroll
      for (int j = 0; j < 12; ++j) {
        int k0 = ci * 4 + j * 64;
        float4 f = *(const float4*)&x2[base + k0];
        s += f.x + f.y + f.z + f.w;
        s2 += f.x * f.x + f.y * f.y + f.z * f.z + f.w * f.w;
        ushort4 u;
        u.x = f2bf(f.x); u.y = f2bf(f.y); u.z = f2bf(f.z); u.w = f2bf(f.w);
        *(ushort4*)&stash[rowl * 776 + k0] = u;
      }
#pragma unroll
      for (int off = 1; off < 16; off <<= 1) {
        s  += __shfl_xor(s, off);
        s2 += __shfl_xor(s2, off);
      }
      if (ci == 0) {
        float mu = s * (1.0f / 768.0f);
        float var = s2 * (1.0f / 768.0f) - mu * mu;
        murs[rowl][0] = mu;
        murs[rowl][1] = rsqrtf(var + 1e-5f);
      }
    }
    __syncthreads();
    {
      int ri = tid & 15, pg = tid >> 4;
      float mu = murs[ri][0], rs = murs[ri][1];
#pragma unroll
      for (int t = 0; t < 6; ++t) {
        int P = pg * 6 + t;                          // piece 0..95
        ushort8 raw = *(const ushort8*)&stash[ri * 776 + P * 8];
        float4 ga = *(const float4*)&g2[P * 8], gb = *(const float4*)&g2[P * 8 + 4];
        float4 ba = *(const float4*)&b2[P * 8], bb = *(const float4*)&b2[P * 8 + 4];
        float gv[8] = {ga.x, ga.y, ga.z, ga.w, gb.x, gb.y, gb.z, gb.w};
        float bv[8] = {ba.x, ba.y, ba.z, ba.w, bb.x, bb.y, bb.z, bb.w};
        ushort8 nv;
#pragma unroll
        for (int ko = 0; ko < 8; ++ko)
          nv[ko] = f2bf((bf2f(raw[ko]) - mu) * rs * gv[ko] + bv[ko]);
        size_t off = ((size_t)rt * 24 + (P >> 2)) * 512 + (P & 3) * 128 + ri * 8;
        *(ushort8*)&nx2f[off] = nv;
      }
    }
  }
}

// ---------------------------------------------------------------------------
// Merged q/k/v GEMM (R5 structure, verified). Block 128x256, waves 2x2 of
// 64x128, 16x16x32 bf16 MFMA. A-frags direct from fragment-major global;
// B staged fragment-major into dbuf LDS; raw vmcnt(8)+barrier pipeline.
//   [0,512):    q = softmax(nx1 @ Wq + bq), nk=32, bm=id&127
//   [512,768):  k = softmax(nx2 @ Wk + bk), nk=24, bm=id&63
//   [768,1024): v =          nx2 @ Wv + bv
// id%8 == bm%8 -> A-tile sharers on one XCD.
// ---------------------------------------------------------------------------
__global__ __launch_bounds__(256, 2) void gemm_qkv_kernel(
    const bf16_t* __restrict__ nx1f, const bf16_t* __restrict__ Wqf,
    const float* __restrict__ bq, bf16_t* __restrict__ qout,
    const bf16_t* __restrict__ nx2f, const bf16_t* __restrict__ Wkf,
    const float* __restrict__ bk, bf16_t* __restrict__ kout,
    const bf16_t* __restrict__ Wvf, const float* __restrict__ bv,
    bf16_t* __restrict__ vout) {
  __shared__ bf16_t Bs[2 * 16 * 512];
  int id = blockIdx.x;
  const bf16_t *A, *BT; const float* bias; bf16_t* out;
  int nk, bm, bn, do_softmax;
  if (id < 512) {
    A = nx1f; BT = Wqf; bias = bq; out = qout; nk = 32;
    bm = id & 127; bn = id >> 7; do_softmax = 1;
  } else if (id < 768) {
    id -= 512; A = nx2f; BT = Wkf; bias = bk; out = kout; nk = 24;
    bm = id & 63; bn = id >> 6; do_softmax = 1;
  } else {
    id -= 768; A = nx2f; BT = Wvf; bias = bv; out = vout; nk = 24;
    bm = id & 63; bn = id >> 6; do_softmax = 0;
  }
  int tid = threadIdx.x, lane = tid & 63, wid = tid >> 6;
  int wm = wid & 1, wn = wid >> 1;

  const bf16_t* ap[4];
#pragma unroll
  for (int mi = 0; mi < 4; ++mi)
    ap[mi] = A + ((size_t)(bm * 8 + wm * 4 + mi) * nk) * 512 + lane * 8;
  const bf16_t* sp[4];
#pragma unroll
  for (int i = 0; i < 4; ++i)
    sp[i] = BT + ((size_t)(bn * 16 + wid * 4 + i) * nk) * 512 + lane * 8;

  f32x4 acc[4][8];
#pragma unroll
  for (int i = 0; i < 4; ++i)
#pragma unroll
    for (int j = 0; j < 8; ++j) acc[i][j] = {0.f, 0.f, 0.f, 0.f};

  bf16x8 acur[4], anxt[4];
  // prologue: stage kt=0 into buf0, load A-frags kt=0
#pragma unroll
  for (int i = 0; i < 4; ++i)
    gld16(sp[i], (void*)&Bs[(wid * 4 + i) * 512 + lane * 8]);
#pragma unroll
  for (int mi = 0; mi < 4; ++mi) acur[mi] = *(const bf16x8*)ap[mi];

  for (int kt = 0; kt < nk; ++kt) {
    int cb = kt & 1;
    if (kt + 1 < nk) {
      int nb = cb ^ 1;
#pragma unroll
      for (int i = 0; i < 4; ++i)
        gld16(sp[i] + (kt + 1) * 512, (void*)&Bs[nb * 8192 + (wid * 4 + i) * 512 + lane * 8]);
#pragma unroll
      for (int mi = 0; mi < 4; ++mi) anxt[mi] = *(const bf16x8*)(ap[mi] + (kt + 1) * 512);
      // wait only the PREVIOUS iter's 8 vmem (stage kt + A kt); the 8 just
      // issued stay in flight across the barrier.
      asm volatile("s_waitcnt vmcnt(8)\n\ts_barrier" ::: "memory");
    } else {
      asm volatile("s_waitcnt vmcnt(0)\n\ts_barrier" ::: "memory");
    }
    bf16x8 bfr[8];
#pragma unroll
    for (int ni = 0; ni < 8; ++ni)
      bfr[ni] = *(const bf16x8*)&Bs[cb * 8192 + (wn * 8 + ni) * 512 + lane * 8];
#pragma unroll
    for (int mi = 0; mi < 4; ++mi)
#pragma unroll
      for (int ni = 0; ni < 8; ++ni)
        acc[mi][ni] = __builtin_amdgcn_mfma_f32_16x16x32_bf16(acur[mi], bfr[ni], acc[mi][ni], 0, 0, 0);
    // all waves must finish reading Bs[cb] before anyone stages kt+2 into it
    asm volatile("s_waitcnt lgkmcnt(0)\n\ts_barrier" ::: "memory");
#pragma unroll
    for (int mi = 0; mi < 4; ++mi) acur[mi] = anxt[mi];
  }

  int colg0 = bn * 256 + wn * 128;
  float bvv[8];
#pragma unroll
  for (int ni = 0; ni < 8; ++ni) bvv[ni] = bias[colg0 + ni * 16 + (lane & 15)];
#pragma unroll
  for (int mi = 0; mi < 4; ++mi) {
#pragma unroll
    for (int r = 0; r < 4; ++r) {
      int row = bm * 128 + wm * 64 + mi * 16 + (lane >> 4) * 4 + r;
      float vx[8];
#pragma unroll
      for (int ni = 0; ni < 8; ++ni) vx[ni] = acc[mi][ni][r] + bvv[ni];
      if (do_softmax) {
        // two heads per wave span; logits ~N(0,1): exp w/o max-pass is safe
#pragma unroll
        for (int g = 0; g < 2; ++g) {
          float ssum = 0.f;
#pragma unroll
          for (int j = 0; j < 4; ++j) { vx[g * 4 + j] = __expf(vx[g * 4 + j]); ssum += vx[g * 4 + j]; }
#pragma unroll
          for (int off = 1; off < 16; off <<= 1) ssum += __shfl_xor(ssum, off);
          float inv = 1.0f / ssum;
#pragma unroll
          for (int j = 0; j < 4; ++j) vx[g * 4 + j] *= inv;
        }
      }
#pragma unroll
      for (int ni = 0; ni < 8; ++ni)
        out[(size_t)row * 1024 + colg0 + ni * 16 + (lane & 15)] = f2bf(vx[ni]);
    }
  }
}

// ---------------------------------------------------------------------------
// attn partials (R9: MFMA). Block = (bh, n-chunk of 256), 256 thr = 4 waves.
// C[64 d][64 l] += K^T V over the chunk. Stage K^T and V^T in LDS (rows of
// 40 elems = 80B, 16B-aligned b128 reads); per 32-n sub-chunk one K-step:
// wave w computes d-strip [w*16,(w+1)*16) x 64 l = 4 MFMA.
// Fragment conventions identical to the verified GEMMs:
//   a-frag = A[lane&15][(lane>>4)*8 + j], b-frag = B[(lane>>4)*8+j][lane&15],
//   D: col=lane&15, row=(lane>>4)*4+r.
// ---------------------------------------------------------------------------
__global__ __launch_bounds__(256) void attn_partial_kernel(
    const bf16_t* __restrict__ kq, const bf16_t* __restrict__ vq,
    float* __restrict__ part) {
  int bh = blockIdx.x >> 3, c = blockIdx.x & 7;
  int b = bh >> 4, h = bh & 15;
  int tid = threadIdx.x, lane = tid & 63, wid = tid >> 6;
  __shared__ bf16_t Kt[64][40];                  // Kt[d][n] = k[n][d]
  __shared__ bf16_t Vt[64][40];                  // Vt[l][n] = v[n][l]
  f32x4 acc[4];
#pragma unroll
  for (int ni = 0; ni < 4; ++ni) acc[ni] = {0.f, 0.f, 0.f, 0.f};
  int nl = tid & 31, d0 = (tid >> 5) * 8;
  int m = lane & 15, kp = lane >> 4;

  for (int s = 0; s < 8; ++s) {
    int n = c * 256 + s * 32 + nl;
    size_t goff = ((size_t)(b * 2048 + n)) * 1024 + h * 64 + d0;
    ushort8 lk = *(const ushort8*)&kq[goff];     // 8 d's of one n (K)
    ushort8 lv = *(const ushort8*)&vq[goff];     // 8 l's of one n (V)
    __syncthreads();                             // prev chunk's reads done
#pragma unroll
    for (int j = 0; j < 8; ++j) {
      Kt[d0 + j][nl] = lk[j];
      Vt[d0 + j][nl] = lv[j];
    }
    __syncthreads();
    bf16x8 af = *(const bf16x8*)&Kt[wid * 16 + m][kp * 8];
#pragma unroll
    for (int ni = 0; ni < 4; ++ni) {
      bf16x8 bf = *(const bf16x8*)&Vt[ni * 16 + m][kp * 8];
      acc[ni] = __builtin_amdgcn_mfma_f32_16x16x32_bf16(af, bf, acc[ni], 0, 0, 0);
    }
  }
#pragma unroll
  for (int ni = 0; ni < 4; ++ni)
#pragma unroll
    for (int r = 0; r < 4; ++r) {
      int d = wid * 16 + kp * 4 + r;
      int l = ni * 16 + m;
      part[(((size_t)bh * 8 + c) * 64 + d) * 64 + l] = acc[ni][r];
    }
}

// attnT[bh][l][d] = bf16( sum_c partial[bh][c][d][l] )
__global__ __launch_bounds__(256) void attn_finalize_kernel(
    const float* __restrict__ part, bf16_t* __restrict__ attnT) {
  int bh = blockIdx.x, tid = threadIdx.x;
  for (int t = tid; t < 4096; t += 256) {
    int d = t >> 6, l = t & 63;
    float s = 0.f;
#pragma unroll
    for (int c = 0; c < 8; ++c)
      s += part[(((size_t)bh * 8 + c) * 64 + d) * 64 + l];
    attnT[((size_t)bh * 64 + l) * 64 + d] = f2bf(s);
  }
}

// ---------------------------------------------------------------------------
// Final GEMM: out = x1 @ Wh + bh + q @ blockdiag(attn), fp32 out.
// R5 pipeline (A = x1f fragment-major direct, B = Whf staged dbuf).
// grid (128, 4), bm fast. y-tail: 2 direct K-steps on (qb, attnT).
// ---------------------------------------------------------------------------
__global__ __launch_bounds__(256, 2) void gemm_final_kernel(
    const bf16_t* __restrict__ x1f, const bf16_t* __restrict__ Whf,
    const float* __restrict__ bias, const bf16_t* __restrict__ qb,
    const bf16_t* __restrict__ attnT, float* __restrict__ out) {
  __shared__ bf16_t Bs[2 * 16 * 512];
  const int nk = 32;
  int tid = threadIdx.x;
  int bm = blockIdx.x, bn = blockIdx.y;
  int lane = tid & 63, wid = tid >> 6;
  int wm = wid & 1, wn = wid >> 1;
  int b = bm >> 5;                       // 32 m-tiles per batch
  int klane = (lane >> 4) * 8;

  const bf16_t* ap[4];
#pragma unroll
  for (int mi = 0; mi < 4; ++mi)
    ap[mi] = x1f + ((size_t)(bm * 8 + wm * 4 + mi) * nk) * 512 + lane * 8;
  const bf16_t* sp[4];
#pragma unroll
  for (int i = 0; i < 4; ++i)
    sp[i] = Whf + ((size_t)(bn * 16 + wid * 4 + i) * nk) * 512 + lane * 8;

  f32x4 acc[4][8];
#pragma unroll
  for (int i = 0; i < 4; ++i)
#pragma unroll
    for (int j = 0; j < 8; ++j) acc[i][j] = {0.f, 0.f, 0.f, 0.f};

  bf16x8 acur[4], anxt[4];
#pragma unroll
  for (int i = 0; i < 4; ++i)
    gld16(sp[i], (void*)&Bs[(wid * 4 + i) * 512 + lane * 8]);
#pragma unroll
  for (int mi = 0; mi < 4; ++mi) acur[mi] = *(const bf16x8*)ap[mi];

  for (int kt = 0; kt < nk; ++kt) {
    int cb = kt & 1;
    if (kt + 1 < nk) {
      int nb = cb ^ 1;
#pragma unroll
      for (int i = 0; i < 4; ++i)
        gld16(sp[i] + (kt + 1) * 512, (void*)&Bs[nb * 8192 + (wid * 4 + i) * 512 + lane * 8]);
#pragma unroll
      for (int mi = 0; mi < 4; ++mi) anxt[mi] = *(const bf16x8*)(ap[mi] + (kt + 1) * 512);
      asm volatile("s_waitcnt vmcnt(8)\n\ts_barrier" ::: "memory");
    } else {
      asm volatile("s_waitcnt vmcnt(0)\n\ts_barrier" ::: "memory");
    }
    bf16x8 bfr[8];
#pragma unroll
    for (int ni = 0; ni < 8; ++ni)
      bfr[ni] = *(const bf16x8*)&Bs[cb * 8192 + (wn * 8 + ni) * 512 + lane * 8];
#pragma unroll
    for (int mi = 0; mi < 4; ++mi)
#pragma unroll
      for (int ni = 0; ni < 8; ++ni)
        acc[mi][ni] = __builtin_amdgcn_mfma_f32_16x16x32_bf16(acur[mi], bfr[ni], acc[mi][ni], 0, 0, 0);
    asm volatile("s_waitcnt lgkmcnt(0)\n\ts_barrier" ::: "memory");
#pragma unroll
    for (int mi = 0; mi < 4; ++mi) acur[mi] = anxt[mi];
  }

  // --- y tail: 2 K-steps on (q, attnT). Wave cols = heads h0, h0+1. ---
  {
    int h0 = bn * 4 + wn * 2;
#pragma unroll
    for (int k2 = 0; k2 < 2; ++k2) {
      bf16x8 aq[2][4], bt[8];
#pragma unroll
      for (int g = 0; g < 2; ++g)
#pragma unroll
        for (int mi = 0; mi < 4; ++mi)
          aq[g][mi] = *(const bf16x8*)(qb
              + (size_t)(bm * 128 + wm * 64 + mi * 16 + (lane & 15)) * 1024
              + (h0 + g) * 64 + k2 * 32 + klane);
#pragma unroll
      for (int ni = 0; ni < 8; ++ni)
        bt[ni] = *(const bf16x8*)(attnT
            + ((size_t)(b * 16 + h0 + (ni >> 2)) * 64 + (ni & 3) * 16 + (lane & 15)) * 64
            + k2 * 32 + klane);
#pragma unroll
      for (int mi = 0; mi < 4; ++mi)
#pragma unroll
        for (int ni = 0; ni < 8; ++ni)
          acc[mi][ni] = __builtin_amdgcn_mfma_f32_16x16x32_bf16(aq[ni >> 2][mi], bt[ni], acc[mi][ni], 0, 0, 0);
    }
  }

  int colg0 = bn * 256 + wn * 128;
  float bvv[8];
#pragma unroll
  for (int ni = 0; ni < 8; ++ni) bvv[ni] = bias[colg0 + ni * 16 + (lane & 15)];
#pragma unroll
  for (int mi = 0; mi < 4; ++mi)
#pragma unroll
    for (int r = 0; r < 4; ++r) {
      int row = bm * 128 + wm * 64 + mi * 16 + (lane >> 4) * 4 + r;
#pragma unroll
      for (int ni = 0; ni < 8; ++ni)
        out[(size_t)row * 1024 + colg0 + ni * 16 + (lane & 15)] = acc[mi][ni][r] + bvv[ni];
    }
}

// ---------------------------------------------------------------------------
extern "C" void kernel_launch(void* const* d_in, const int* in_sizes, int n_in,
                              void* d_out, int out_size, void* d_ws, size_t ws_size,
                              hipStream_t stream) {
  const float* x1 = (const float*)d_in[0];
  const float* x2 = (const float*)d_in[1];
  const float* Wq = (const float*)d_in[2];
  const float* bq = (const float*)d_in[3];
  const float* Wk = (const float*)d_in[4];
  const float* bk = (const float*)d_in[5];
  const float* Wv = (const float*)d_in[6];
  const float* bv = (const float*)d_in[7];
  const float* Wh = (const float*)d_in[8];
  const float* bh = (const float*)d_in[9];
  const float* g1 = (const float*)d_in[10];
  const float* b1 = (const float*)d_in[11];
  const float* g2 = (const float*)d_in[12];
  const float* b2 = (const float*)d_in[13];
  float* out = (float*)d_out;

  char* w = (char*)d_ws;
  bf16_t* nx1f = (bf16_t*)w; w += (size_t)16384 * 1024 * 2;
  bf16_t* x1f  = (bf16_t*)w; w += (size_t)16384 * 1024 * 2;
  bf16_t* nx2f = (bf16_t*)w; w += (size_t)8192 * 768 * 2;
  bf16_t* Wqf  = (bf16_t*)w; w += (size_t)1024 * 1024 * 2;
  bf16_t* Wkf  = (bf16_t*)w; w += (size_t)1024 * 768 * 2;
  bf16_t* Wvf  = (bf16_t*)w; w += (size_t)1024 * 768 * 2;
  bf16_t* Whf  = (bf16_t*)w; w += (size_t)1024 * 1024 * 2;
  bf16_t* qb   = (bf16_t*)w; w += (size_t)16384 * 1024 * 2;
  bf16_t* kbuf = (bf16_t*)w; w += (size_t)8192 * 1024 * 2;
  bf16_t* vbuf = (bf16_t*)w; w += (size_t)8192 * 1024 * 2;
  float*  part = (float*)w;  w += (size_t)64 * 8 * 64 * 64 * 4;
  bf16_t* attnT = (bf16_t*)w; w += (size_t)64 * 64 * 64 * 2;

  prep_kernel<<<dim3(5120), dim3(256), 0, stream>>>(
      Wq, Wk, Wv, Wh, Wqf, Wkf, Wvf, Whf,
      x1, g1, b1, nx1f, x1f, x2, g2, b2, nx2f);
  gemm_qkv_kernel<<<dim3(1024), dim3(256), 0, stream>>>(
      nx1f, Wqf, bq, qb, nx2f, Wkf, bk, kbuf, Wvf, bv, vbuf);
  attn_partial_kernel<<<dim3(512), dim3(256), 0, stream>>>(kbuf, vbuf, part);
  attn_finalize_kernel<<<dim3(64), dim3(256), 0, stream>>>(part, attnT);
  gemm_final_kernel<<<dim3(128, 4), dim3(256), 0, stream>>>(x1f, Whf, bh, qb, attnT, out);
}